// Round 1
// baseline (76.158 us; speedup 1.0000x reference)
//
#include <hip/hip_runtime.h>
#include <math.h>

// QuanvolutionHybrid, collapsed form.
// The reference only consumes feats[:, :1] == <Z_0> of patch 0 per image.
// Key algebra: quanv circuit = fixed unitary U (depends only on weights_q).
//   z0 = <psi| U' Z0 U |psi>, and the RX-embedded product state has
//   psi_k = r_k * (-i)^popc(k) with REAL r_k = prod(cos/sin of half-angles).
//   Folding the i-phases into M = U' Z0 U gives a real symmetric G with
//   z0 = r^T G r  (256 fma, no transcendentals per thread).
// qfc chain of 9 shared Rot gates = fixed 2x2 unitary V; with Bloch coeffs
//   H = V' Z V = xH*X + yH*Y + zH*Z  ->  q = cos(z0)*zH - sin(z0)*yH.
// Per block: cooperative precompute of G (via 16 basis-state simulations
// reusing the verified gate code) and (yH,zH); then 1 thread per image.

struct c32 { float re, im; };

__device__ __forceinline__ c32 cmul(c32 a, c32 b) {
    return { fmaf(a.re, b.re, -a.im * b.im), fmaf(a.re, b.im, a.im * b.re) };
}
__device__ __forceinline__ c32 cmulc(c32 a, c32 b) {  // conj(a)*b
    return { fmaf(a.re, b.re, a.im * b.im), fmaf(a.re, b.im, -a.im * b.re) };
}
__device__ __forceinline__ c32 cadd(c32 a, c32 b) { return { a.re + b.re, a.im + b.im }; }
__device__ __forceinline__ c32 csub(c32 a, c32 b) { return { a.re - b.re, a.im - b.im }; }

// Apply 2x2 gate U on wire W of a 4-wire state. Wire w's bit stride = 8>>w.
template<int W>
__device__ __forceinline__ void apply1(c32 amp[16], c32 u00, c32 u01, c32 u10, c32 u11) {
    constexpr int s = 8 >> W;
    #pragma unroll
    for (int i = 0; i < 16; ++i) {
        if (i & s) continue;  // constant-folded after unroll
        c32 a = amp[i], b = amp[i + s];
        amp[i]     = cadd(cmul(u00, a), cmul(u01, b));
        amp[i + s] = cadd(cmul(u10, a), cmul(u11, b));
    }
}

template<int C, int T>
__device__ __forceinline__ void cnot4(c32 amp[16]) {
    constexpr int sc = 8 >> C, st = 8 >> T;
    #pragma unroll
    for (int i = 0; i < 16; ++i) {
        if ((i & sc) && !(i & st)) {
            c32 tmp = amp[i]; amp[i] = amp[i | st]; amp[i | st] = tmp;
        }
    }
}

// PennyLane Rot(phi, theta, omega) = RZ(omega) RY(theta) RZ(phi)
__device__ __forceinline__ void make_rot(float phi, float th, float om,
                                         c32& u00, c32& u01, c32& u10, c32& u11) {
    float sh, ch; sincosf(th * 0.5f, &sh, &ch);
    float spo, cpo; sincosf((phi + om) * 0.5f, &spo, &cpo);
    float spm, cpm; sincosf((phi - om) * 0.5f, &spm, &cpm);
    u00 = {  cpo * ch, -spo * ch };
    u01 = { -cpm * sh, -spm * sh };
    u10 = {  cpm * sh, -spm * sh };
    u11 = {  cpo * ch,  spo * ch };
}

__global__ __launch_bounds__(64)
void quanv_hybrid_kernel(const float* __restrict__ x,
                         const float* __restrict__ wq,    // [2,2,4,3] = 16 gates x 3
                         const float* __restrict__ wfc,   // [3,3,1,3] =  9 gates x 3
                         const float* __restrict__ Wout,  // [10,1]
                         const float* __restrict__ bout,  // [10]
                         float* __restrict__ out,         // [B,10]
                         int B)
{
    const int tid = threadIdx.x;
    const int b = blockIdx.x * 64 + tid;

    __shared__ c32  gmat[25][4];          // 16 quanv Rot + 9 qfc Rot matrices
    __shared__ float Ur[16][16], Ui[16][16]; // U[i][t]: row i, column t
    __shared__ float Gq[16][16];          // real symmetric quadratic form
    __shared__ float yz[2];               // {yH, zH}

    // ---- Phase 0: 25 Rot matrices, one per thread (3 sincosf each) ----
    if (tid < 25) {
        const float* p = (tid < 16) ? (wq + 3 * tid) : (wfc + 3 * (tid - 16));
        c32 a, bb, c, d;
        make_rot(p[0], p[1], p[2], a, bb, c, d);
        gmat[tid][0] = a; gmat[tid][1] = bb; gmat[tid][2] = c; gmat[tid][3] = d;
    }
    __syncthreads();

    // ---- Phase 1: threads 0..15 simulate basis columns of U; thread 16 builds V ----
    if (tid < 16) {
        c32 amp[16];
        #pragma unroll
        for (int i = 0; i < 16; ++i) amp[i] = { 0.f, 0.f };
        amp[tid].re = 1.f;

        #pragma unroll
        for (int al = 0; al < 4; ++al) {   // al = app*2 + l ; ranges = (1,2)
            apply1<0>(amp, gmat[al*4+0][0], gmat[al*4+0][1], gmat[al*4+0][2], gmat[al*4+0][3]);
            apply1<1>(amp, gmat[al*4+1][0], gmat[al*4+1][1], gmat[al*4+1][2], gmat[al*4+1][3]);
            apply1<2>(amp, gmat[al*4+2][0], gmat[al*4+2][1], gmat[al*4+2][2], gmat[al*4+2][3]);
            apply1<3>(amp, gmat[al*4+3][0], gmat[al*4+3][1], gmat[al*4+3][2], gmat[al*4+3][3]);
            if ((al & 1) == 0) {           // layer 0: r = 1
                cnot4<0,1>(amp); cnot4<1,2>(amp); cnot4<2,3>(amp); cnot4<3,0>(amp);
            } else {                       // layer 1: r = 2
                cnot4<0,2>(amp); cnot4<1,3>(amp); cnot4<2,0>(amp); cnot4<3,1>(amp);
            }
        }
        #pragma unroll
        for (int i = 0; i < 16; ++i) { Ur[i][tid] = amp[i].re; Ui[i][tid] = amp[i].im; }
    } else if (tid == 16) {
        // V = U9 ... U1 (applied left-multiplying in gate order)
        c32 v00 = {1.f, 0.f}, v01 = {0.f, 0.f}, v10 = {0.f, 0.f}, v11 = {1.f, 0.f};
        #pragma unroll
        for (int g = 0; g < 9; ++g) {
            c32 u00 = gmat[16+g][0], u01 = gmat[16+g][1], u10 = gmat[16+g][2], u11 = gmat[16+g][3];
            c32 n00 = cadd(cmul(u00, v00), cmul(u01, v10));
            c32 n01 = cadd(cmul(u00, v01), cmul(u01, v11));
            c32 n10 = cadd(cmul(u10, v00), cmul(u11, v10));
            c32 n11 = cadd(cmul(u10, v01), cmul(u11, v11));
            v00 = n00; v01 = n01; v10 = n10; v11 = n11;
        }
        // H = V' Z V: zH = H00 (= -H11), H01 = conj(v00)v01 - conj(v10)v11, yH = -Im H01
        float zH = fmaf(v00.re, v00.re, v00.im * v00.im)
                 - fmaf(v10.re, v10.re, v10.im * v10.im);
        c32 h01 = csub(cmulc(v00, v01), cmulc(v10, v11));
        yz[0] = -h01.im; yz[1] = zH;
    }
    __syncthreads();

    // ---- Phase 2: G[j][k] = Re[ (sum_i s_i conj(U_ij) U_ik) * i^(popc(j)-popc(k)) ] ----
    #pragma unroll
    for (int e = 0; e < 4; ++e) {
        int n = tid * 4 + e, j = n >> 4, k = n & 15;
        float mre = 0.f, mim = 0.f;
        #pragma unroll
        for (int i = 0; i < 16; ++i) {
            float ar = Ur[i][j], ai = Ui[i][j], br = Ur[i][k], bi = Ui[i][k];
            float re = fmaf(ar, br,  ai * bi);   // conj(a)*b, real part
            float im = fmaf(ar, bi, -ai * br);   // imag part
            if (i < 8) { mre += re; mim += im; } else { mre -= re; mim -= im; }
        }
        int m = (__popc(j) - __popc(k)) & 3;
        float g = (m == 0) ? mre : (m == 1) ? -mim : (m == 2) ? -mre : mim;
        Gq[j][k] = g;
    }
    __syncthreads();

    if (b >= B) return;

    // ---- Phase 3: per-image work ----
    const float* xb = x + (size_t)b * 784;
    float ang0 = xb[0], ang1 = xb[1], ang2 = xb[28], ang3 = xb[29];

    float s0, c0, s1, c1, s2, c2, s3, c3;
    sincosf(ang0 * 0.5f, &s0, &c0);
    sincosf(ang1 * 0.5f, &s1, &c1);
    sincosf(ang2 * 0.5f, &s2, &c2);
    sincosf(ang3 * 0.5f, &s3, &c3);

    // r_k = prod over wires of (cos or sin); wire0 = MSB (bit 8)
    float A[4] = { c0 * c1, c0 * s1, s0 * c1, s0 * s1 };   // wires 0,1
    float Bv[4] = { c2 * c3, c2 * s3, s2 * c3, s2 * s3 };  // wires 2,3
    float r[16];
    #pragma unroll
    for (int k = 0; k < 16; ++k) r[k] = A[k >> 2] * Bv[k & 3];  // indices const after unroll

    float z0 = 0.f;
    #pragma unroll
    for (int j = 0; j < 16; ++j) {
        float t = 0.f;
        #pragma unroll
        for (int k = 0; k < 16; ++k) t = fmaf(Gq[j][k], r[k], t);
        z0 = fmaf(r[j], t, z0);
    }

    // qfc: q = cos(z0)*zH - sin(z0)*yH
    float sz, cz; sincosf(z0, &sz, &cz);
    float q = fmaf(cz, yz[1], -sz * yz[0]);

    // Linear(1,10) + log_softmax
    float lg[10], m = -1e30f;
    #pragma unroll
    for (int j = 0; j < 10; ++j) {
        lg[j] = fmaf(q, Wout[j], bout[j]);
        m = fmaxf(m, lg[j]);
    }
    float sum = 0.f;
    #pragma unroll
    for (int j = 0; j < 10; ++j) sum += expf(lg[j] - m);
    float lse = m + logf(sum);

    float* ob = out + (size_t)b * 10;
    #pragma unroll
    for (int j = 0; j < 10; ++j) ob[j] = lg[j] - lse;
}

extern "C" void kernel_launch(void* const* d_in, const int* in_sizes, int n_in,
                              void* d_out, int out_size, void* d_ws, size_t ws_size,
                              hipStream_t stream) {
    const float* x    = (const float*)d_in[0];
    const float* wq   = (const float*)d_in[1];
    const float* wfc  = (const float*)d_in[2];
    const float* Wout = (const float*)d_in[3];
    const float* bout = (const float*)d_in[4];
    float* out = (float*)d_out;

    int B = in_sizes[0] / 784;  // 4096
    const int threads = 64;
    int blocks = (B + threads - 1) / threads;
    quanv_hybrid_kernel<<<blocks, threads, 0, stream>>>(x, wq, wfc, Wout, bout, out, B);
}

// Round 2
// 74.879 us; speedup vs baseline: 1.0171x; 1.0171x over previous
//
#include <hip/hip_runtime.h>
#include <math.h>

// QuanvolutionHybrid, collapsed form, 16-lanes-per-image parallel version.
// Math identical to the previous passing kernel:
//   z0 = r^T G r   (G = real form of U' Z0 U with embedding i-phases folded in)
//   q  = cos(z0)*zH - sin(z0)*yH   (qfc chain collapsed to Bloch coeffs of V'ZV)
// Restructure for latency hiding: 16 lanes cooperate per image (j-slice of the
// quadratic form + lane-parallel log_softmax), 256 threads/block, 256 blocks
// -> 1024 waves instead of 64. x/Wout/bout loads hoisted above the barriers so
// their latency overlaps the per-block G precompute.

struct c32 { float re, im; };

__device__ __forceinline__ c32 cmul(c32 a, c32 b) {
    return { fmaf(a.re, b.re, -a.im * b.im), fmaf(a.re, b.im, a.im * b.re) };
}
__device__ __forceinline__ c32 cmulc(c32 a, c32 b) {  // conj(a)*b
    return { fmaf(a.re, b.re, a.im * b.im), fmaf(a.re, b.im, -a.im * b.re) };
}
__device__ __forceinline__ c32 cadd(c32 a, c32 b) { return { a.re + b.re, a.im + b.im }; }
__device__ __forceinline__ c32 csub(c32 a, c32 b) { return { a.re - b.re, a.im - b.im }; }

template<int W>
__device__ __forceinline__ void apply1(c32 amp[16], c32 u00, c32 u01, c32 u10, c32 u11) {
    constexpr int s = 8 >> W;
    #pragma unroll
    for (int i = 0; i < 16; ++i) {
        if (i & s) continue;  // constant-folded after unroll
        c32 a = amp[i], b = amp[i + s];
        amp[i]     = cadd(cmul(u00, a), cmul(u01, b));
        amp[i + s] = cadd(cmul(u10, a), cmul(u11, b));
    }
}

template<int C, int T>
__device__ __forceinline__ void cnot4(c32 amp[16]) {
    constexpr int sc = 8 >> C, st = 8 >> T;
    #pragma unroll
    for (int i = 0; i < 16; ++i) {
        if ((i & sc) && !(i & st)) {
            c32 tmp = amp[i]; amp[i] = amp[i | st]; amp[i | st] = tmp;
        }
    }
}

// PennyLane Rot(phi, theta, omega) = RZ(omega) RY(theta) RZ(phi)
__device__ __forceinline__ void make_rot(float phi, float th, float om,
                                         c32& u00, c32& u01, c32& u10, c32& u11) {
    float sh, ch; sincosf(th * 0.5f, &sh, &ch);
    float spo, cpo; sincosf((phi + om) * 0.5f, &spo, &cpo);
    float spm, cpm; sincosf((phi - om) * 0.5f, &spm, &cpm);
    u00 = {  cpo * ch, -spo * ch };
    u01 = { -cpm * sh, -spm * sh };
    u10 = {  cpm * sh, -spm * sh };
    u11 = {  cpo * ch,  spo * ch };
}

#define GP 20  // padded row stride of Gq in floats (breaks 64B-stride bank conflicts)

__global__ __launch_bounds__(256)
void quanv_hybrid_kernel(const float* __restrict__ x,
                         const float* __restrict__ wq,    // [2,2,4,3] = 16 gates x 3
                         const float* __restrict__ wfc,   // [3,3,1,3] =  9 gates x 3
                         const float* __restrict__ Wout,  // [10,1]
                         const float* __restrict__ bout,  // [10]
                         float* __restrict__ out,         // [B,10]
                         int B)
{
    const int tid = threadIdx.x;
    const int j   = tid & 15;          // this lane's j-slice / output index
    const int img = blockIdx.x * 16 + (tid >> 4);
    const int imgc = (img < B) ? img : (B - 1);   // clamp for safe loads

    __shared__ c32   gmat[25][4];       // 16 quanv Rot + 9 qfc Rot matrices
    __shared__ float Ur[16][16], Ui[16][16];
    __shared__ float Gqs[16 * GP];      // padded real quadratic form
    __shared__ float yz[2];             // {yH, zH}

    // ---- Hoisted global loads: latency overlaps the precompute phases ----
    const float* xb = x + (size_t)imgc * 784;
    float2 a01 = *reinterpret_cast<const float2*>(xb);        // img[0,0..1]
    float2 a23 = *reinterpret_cast<const float2*>(xb + 28);   // img[1,0..1]
    float Wj = (j < 10) ? Wout[j] : 0.f;
    float bj = (j < 10) ? bout[j] : 0.f;

    // ---- Phase 0: 25 Rot matrices, one per thread ----
    if (tid < 25) {
        const float* p = (tid < 16) ? (wq + 3 * tid) : (wfc + 3 * (tid - 16));
        c32 a, bb, c, d;
        make_rot(p[0], p[1], p[2], a, bb, c, d);
        gmat[tid][0] = a; gmat[tid][1] = bb; gmat[tid][2] = c; gmat[tid][3] = d;
    }
    __syncthreads();

    // ---- Phase 1: threads 0..15 simulate basis columns of U; thread 16 builds V ----
    if (tid < 16) {
        c32 amp[16];
        #pragma unroll
        for (int i = 0; i < 16; ++i) amp[i] = { 0.f, 0.f };
        amp[tid].re = 1.f;

        #pragma unroll
        for (int al = 0; al < 4; ++al) {   // al = app*2 + l ; ranges = (1,2)
            apply1<0>(amp, gmat[al*4+0][0], gmat[al*4+0][1], gmat[al*4+0][2], gmat[al*4+0][3]);
            apply1<1>(amp, gmat[al*4+1][0], gmat[al*4+1][1], gmat[al*4+1][2], gmat[al*4+1][3]);
            apply1<2>(amp, gmat[al*4+2][0], gmat[al*4+2][1], gmat[al*4+2][2], gmat[al*4+2][3]);
            apply1<3>(amp, gmat[al*4+3][0], gmat[al*4+3][1], gmat[al*4+3][2], gmat[al*4+3][3]);
            if ((al & 1) == 0) {           // layer 0: r = 1
                cnot4<0,1>(amp); cnot4<1,2>(amp); cnot4<2,3>(amp); cnot4<3,0>(amp);
            } else {                       // layer 1: r = 2
                cnot4<0,2>(amp); cnot4<1,3>(amp); cnot4<2,0>(amp); cnot4<3,1>(amp);
            }
        }
        #pragma unroll
        for (int i = 0; i < 16; ++i) { Ur[i][tid] = amp[i].re; Ui[i][tid] = amp[i].im; }
    } else if (tid == 16) {
        // V = U9 ... U1
        c32 v00 = {1.f, 0.f}, v01 = {0.f, 0.f}, v10 = {0.f, 0.f}, v11 = {1.f, 0.f};
        #pragma unroll
        for (int g = 0; g < 9; ++g) {
            c32 u00 = gmat[16+g][0], u01 = gmat[16+g][1], u10 = gmat[16+g][2], u11 = gmat[16+g][3];
            c32 n00 = cadd(cmul(u00, v00), cmul(u01, v10));
            c32 n01 = cadd(cmul(u00, v01), cmul(u01, v11));
            c32 n10 = cadd(cmul(u10, v00), cmul(u11, v10));
            c32 n11 = cadd(cmul(u10, v01), cmul(u11, v11));
            v00 = n00; v01 = n01; v10 = n10; v11 = n11;
        }
        float zH = fmaf(v00.re, v00.re, v00.im * v00.im)
                 - fmaf(v10.re, v10.re, v10.im * v10.im);
        c32 h01 = csub(cmulc(v00, v01), cmulc(v10, v11));
        yz[0] = -h01.im; yz[1] = zH;
    }
    __syncthreads();

    // ---- Phase 2: one Gq entry per thread (256 entries, 256 threads) ----
    {
        int jj = tid >> 4, kk = tid & 15;
        float mre = 0.f, mim = 0.f;
        #pragma unroll
        for (int i = 0; i < 16; ++i) {
            float ar = Ur[i][jj], ai = Ui[i][jj], br = Ur[i][kk], bi = Ui[i][kk];
            float re = fmaf(ar, br,  ai * bi);
            float im = fmaf(ar, bi, -ai * br);
            if (i < 8) { mre += re; mim += im; } else { mre -= re; mim -= im; }
        }
        int m4 = (__popc(jj) - __popc(kk)) & 3;
        float g = (m4 == 0) ? mre : (m4 == 1) ? -mim : (m4 == 2) ? -mre : mim;
        Gqs[jj * GP + kk] = g;
    }
    __syncthreads();

    // ---- Phase 3: per-image, 16 lanes cooperate ----
    float s0, c0, s1, c1, s2, c2, s3, c3;
    sincosf(a01.x * 0.5f, &s0, &c0);
    sincosf(a01.y * 0.5f, &s1, &c1);
    sincosf(a23.x * 0.5f, &s2, &c2);
    sincosf(a23.y * 0.5f, &s3, &c3);

    float A[4]  = { c0 * c1, c0 * s1, s0 * c1, s0 * s1 };   // wires 0,1
    float Bv[4] = { c2 * c3, c2 * s3, s2 * c3, s2 * s3 };   // wires 2,3
    float r[16];
    #pragma unroll
    for (int k = 0; k < 16; ++k) r[k] = A[k >> 2] * Bv[k & 3];

    // t_j = sum_k Gq[j][k] r[k]; z0 = sum_j r[j] t_j (16-lane tree reduce)
    const float* gr = &Gqs[j * GP];
    float4 g0 = *reinterpret_cast<const float4*>(gr + 0);
    float4 g1 = *reinterpret_cast<const float4*>(gr + 4);
    float4 g2 = *reinterpret_cast<const float4*>(gr + 8);
    float4 g3 = *reinterpret_cast<const float4*>(gr + 12);
    float t = 0.f;
    t = fmaf(g0.x, r[0],  t); t = fmaf(g0.y, r[1],  t);
    t = fmaf(g0.z, r[2],  t); t = fmaf(g0.w, r[3],  t);
    t = fmaf(g1.x, r[4],  t); t = fmaf(g1.y, r[5],  t);
    t = fmaf(g1.z, r[6],  t); t = fmaf(g1.w, r[7],  t);
    t = fmaf(g2.x, r[8],  t); t = fmaf(g2.y, r[9],  t);
    t = fmaf(g2.z, r[10], t); t = fmaf(g2.w, r[11], t);
    t = fmaf(g3.x, r[12], t); t = fmaf(g3.y, r[13], t);
    t = fmaf(g3.z, r[14], t); t = fmaf(g3.w, r[15], t);

    float z0 = r[j] * t;
    z0 += __shfl_xor(z0, 1);
    z0 += __shfl_xor(z0, 2);
    z0 += __shfl_xor(z0, 4);
    z0 += __shfl_xor(z0, 8);   // all 16 lanes of the group now hold z0

    // qfc: q = cos(z0)*zH - sin(z0)*yH
    float sz, cz; sincosf(z0, &sz, &cz);
    float q = fmaf(cz, yz[1], -sz * yz[0]);

    // Linear(1,10) + log_softmax, lane-parallel over j (lanes 10..15 padded)
    float lg = (j < 10) ? fmaf(q, Wj, bj) : -1e30f;
    float m = lg;
    m = fmaxf(m, __shfl_xor(m, 1));
    m = fmaxf(m, __shfl_xor(m, 2));
    m = fmaxf(m, __shfl_xor(m, 4));
    m = fmaxf(m, __shfl_xor(m, 8));

    float e = (j < 10) ? expf(lg - m) : 0.f;
    float sum = e;
    sum += __shfl_xor(sum, 1);
    sum += __shfl_xor(sum, 2);
    sum += __shfl_xor(sum, 4);
    sum += __shfl_xor(sum, 8);

    float lse = m + logf(sum);
    if (j < 10 && img < B) out[(size_t)img * 10 + j] = lg - lse;
}

extern "C" void kernel_launch(void* const* d_in, const int* in_sizes, int n_in,
                              void* d_out, int out_size, void* d_ws, size_t ws_size,
                              hipStream_t stream) {
    const float* x    = (const float*)d_in[0];
    const float* wq   = (const float*)d_in[1];
    const float* wfc  = (const float*)d_in[2];
    const float* Wout = (const float*)d_in[3];
    const float* bout = (const float*)d_in[4];
    float* out = (float*)d_out;

    int B = in_sizes[0] / 784;          // 4096
    int blocks = (B + 15) / 16;         // 16 images per 256-thread block
    quanv_hybrid_kernel<<<blocks, 256, 0, stream>>>(x, wq, wfc, Wout, bout, out, B);
}